// Round 4
// baseline (218.266 us; speedup 1.0000x reference)
//
#include <hip/hip_runtime.h>

// CIN (xDeepFM) fully-fused kernel for MI355X.
// B=4096, F=32, D=32; layer1: K1=1024 -> N=128; layer2: K2=4096 -> N=128.
// GEMM rows=(b,d); A generated in registers: A[(b,d)][h*M+m] = x0[b,h,d]*prev[b,m,d].
// mfma_f32_32x32x16_f16: wave = 4 b's (128 rows) x 32 cols.
// R4: full software pipeline — x via ds_read_b128 ([h/2][d][bi][h&1] layout,
// prefetched 1 gg-pair ahead), B-frags depth-2, layer-2 B preloaded before
// epilogue-1. No LDS/VMEM wait sits on the pk_mul->MFMA critical path.

typedef _Float16 half_t;
typedef _Float16 half4v __attribute__((ext_vector_type(4)));
typedef _Float16 half8 __attribute__((ext_vector_type(8)));
typedef float f32x16 __attribute__((ext_vector_type(16)));

// ---- W pack (both filters, one launch): Wp[s][tg][n][8], k=h*M+mc*16+tg*8+j.
__global__ void prep_w_kernel(const float* __restrict__ W0,
                              const float* __restrict__ W1,
                              half_t* __restrict__ Wp0,
                              half_t* __restrict__ Wp1) {
  int gid = blockIdx.x * 256 + threadIdx.x;  // 320*256 threads
  int n = gid & 127;
  int tg = (gid >> 7) & 1;
  int s = gid >> 8;  // 0..319
  const float* W;
  half_t* Wp;
  int M, sl;
  if (s < 64) { W = W0; Wp = Wp0; M = 32; sl = s; }
  else        { W = W1; Wp = Wp1; M = 128; sl = s - 64; }
  int h = sl & 31, mc = sl >> 5;
  int kbase = h * M + mc * 16 + tg * 8;
  half8 v;
#pragma unroll
  for (int j = 0; j < 8; ++j) v[j] = (half_t)W[(size_t)(kbase + j) * 128 + n];
  *(half8*)(Wp + ((size_t)(sl * 2 + tg) * 128 + n) * 8) = v;
}

// swizzled prevT index: logical (row, m) -> halfs offset. 16B-chunk XOR spread.
__device__ __forceinline__ int pswz(int row, int m) {
  return row * 128 + (((m >> 3) ^ (row & 15)) << 3) + (m & 7);
}

__device__ __forceinline__ f32x16 mfma3216(half8 a, half8 b, f32x16 c) {
  return __builtin_amdgcn_mfma_f32_32x32x16_f16(a, b, c, 0, 0, 0);
}

// One CIN layer: MC m-chunks x 32 h, fully pipelined.
// Caller must have Bc0,Bc1,Bn0,Bn1 preloaded with s=0,1,2,3 and xq with gg=0.
template <int MC, bool L1>
__device__ __forceinline__ void layer_loop(const half_t* __restrict__ Wp,
                                           const half_t* __restrict__ psrc,
                                           const half_t* __restrict__ xrd,
                                           int woff, int l31, int hi,
                                           f32x16 acc[4], half8& Bc0,
                                           half8& Bc1, half8& Bn0, half8& Bn1,
                                           half8& xq) {
  half8 P[4];
#pragma unroll
  for (int rt = 0; rt < 4; ++rt)
    P[rt] = L1 ? *(const half8*)&psrc[(rt * 32 + l31) * 40 + hi * 8]
               : *(const half8*)&psrc[pswz(rt * 32 + l31, hi * 8)];
#pragma unroll 1
  for (int mc = 0; mc < MC; ++mc) {
#pragma unroll 1
    for (int gg = 0; gg < 16; ++gg) {
      int sn = (mc * 32 + gg * 2 + 4) & (MC * 32 - 1);
      half8 Bf0 = *(const half8*)(Wp + (size_t)sn * 2048 + woff);
      half8 Bf1 = *(const half8*)(Wp + (size_t)(sn + 1) * 2048 + woff);
      half8 xqn = *(const half8*)(xrd + ((gg + 1) & 15) * 256);
#pragma unroll
      for (int rt = 0; rt < 4; ++rt) {
        half8 Af = P[rt] * xq[rt * 2 + 0];
        acc[rt] = mfma3216(Af, Bc0, acc[rt]);
      }
#pragma unroll
      for (int rt = 0; rt < 4; ++rt) {
        half8 Af = P[rt] * xq[rt * 2 + 1];
        acc[rt] = mfma3216(Af, Bc1, acc[rt]);
      }
      Bc0 = Bn0; Bc1 = Bn1; Bn0 = Bf0; Bn1 = Bf1;
      xq = xqn;
    }
    if (mc + 1 < MC) {
      int mn = (mc + 1) * 16;
#pragma unroll
      for (int rt = 0; rt < 4; ++rt)
        P[rt] = L1 ? *(const half8*)&psrc[(rt * 32 + l31) * 40 + mn + hi * 8]
                   : *(const half8*)&psrc[pswz(rt * 32 + l31, mn + hi * 8)];
    }
  }
}

__global__ __launch_bounds__(256, 4) void cin_fused_kernel(
    const float* __restrict__ x0,    // [4096][32][32] fp32
    const half_t* __restrict__ Wp0,  // 64*2048 halfs
    const half_t* __restrict__ Wp1,  // 256*2048 halfs
    float* __restrict__ out) {       // [4096][256]
  __shared__ half_t xsf3[16 * 256];       // [h>>1][d][bi][h&1] f16 (8 KB)
  __shared__ half_t prevT[4 * 32 * 128];  // swizzled [bi][d][m] (32 KB); alias xT
  half_t* xT = prevT;                     // [bi*32+d][h], stride 40 halfs

  const int tid = threadIdx.x;
  const int b0 = blockIdx.x * 4;

  // ---- stage x0 -> xsf3 and xT ----
  const float4* x4 = (const float4*)(x0 + (size_t)b0 * 1024);
#pragma unroll
  for (int r = 0; r < 4; ++r) {
    int q = r * 256 + tid;
    float4 v = x4[q];
    int e = q * 4;
    int bi = e >> 10, h = (e >> 5) & 31, d0 = e & 31;
    half4v hv = {(half_t)v.x, (half_t)v.y, (half_t)v.z, (half_t)v.w};
#pragma unroll
    for (int j = 0; j < 4; ++j) {
      xsf3[(h >> 1) * 256 + (d0 + j) * 8 + bi * 2 + (h & 1)] = hv[j];
      xT[(bi * 32 + d0 + j) * 40 + h] = hv[j];
    }
  }

  const int lane = tid & 63;
  const int l31 = lane & 31;
  const int hi = lane >> 5;
  const int wave = tid >> 6;
  const int n0 = wave * 32;

  const int woff = hi * 1024 + (n0 + l31) * 8;  // per-lane B offset (halfs)
  const half_t* xrd = &xsf3[l31 * 8];           // + gg*256 halfs

  f32x16 acc[4];
#pragma unroll
  for (int rt = 0; rt < 4; ++rt)
#pragma unroll
    for (int r = 0; r < 16; ++r) acc[rt][r] = 0.f;

  half8 Bc0, Bc1, Bn0, Bn1, xq;

  // preload layer-1 B (independent of LDS, issue before barrier)
  Bc0 = *(const half8*)(Wp0 + 0 * 2048 + woff);
  Bc1 = *(const half8*)(Wp0 + 1 * 2048 + woff);
  Bn0 = *(const half8*)(Wp0 + 2 * 2048 + woff);
  Bn1 = *(const half8*)(Wp0 + 3 * 2048 + woff);
  __syncthreads();
  xq = *(const half8*)(xrd);

  // ================= layer 1 =================
  layer_loop<2, true>(Wp0, xT, xrd, woff, l31, hi, acc, Bc0, Bc1, Bn0, Bn1,
                      xq);

  // preload layer-2 B while epilogue runs
  Bc0 = *(const half8*)(Wp1 + 0 * 2048 + woff);
  Bc1 = *(const half8*)(Wp1 + 1 * 2048 + woff);
  Bn0 = *(const half8*)(Wp1 + 2 * 2048 + woff);
  Bn1 = *(const half8*)(Wp1 + 3 * 2048 + woff);
  xq = *(const half8*)(xrd);  // gg=0 again (xsf3 untouched)

  __syncthreads();  // all waves done reading xT before prevT overwrite

  // ---- epilogue 1: relu, cur1 -> prevT (swizzled), d-sum -> out[:, 0:128] ----
#pragma unroll
  for (int rt = 0; rt < 4; ++rt) {
    float s = 0.f;
#pragma unroll
    for (int r = 0; r < 16; ++r) {
      float v = acc[rt][r];
      v = v > 0.f ? v : 0.f;
      s += v;
      int d = (r & 3) + ((r >> 2) << 3) + hi * 4;  // C/D row map (32x32)
      prevT[pswz(rt * 32 + d, n0 + l31)] = (half_t)v;
      acc[rt][r] = 0.f;
    }
    s += __shfl_down(s, 32);
    if (lane < 32) out[(size_t)(b0 + rt) * 256 + n0 + lane] = s;
  }
  __syncthreads();

  // ================= layer 2 =================
  layer_loop<8, false>(Wp1, prevT, xrd, woff, l31, hi, acc, Bc0, Bc1, Bn0,
                       Bn1, xq);

  // ---- epilogue 2: relu, d-sum -> out[:, 128:256] ----
#pragma unroll
  for (int rt = 0; rt < 4; ++rt) {
    float s = 0.f;
#pragma unroll
    for (int r = 0; r < 16; ++r) {
      float v = acc[rt][r];
      s += v > 0.f ? v : 0.f;
    }
    s += __shfl_down(s, 32);
    if (lane < 32) out[(size_t)(b0 + rt) * 256 + 128 + n0 + lane] = s;
  }
}

extern "C" void kernel_launch(void* const* d_in, const int* in_sizes, int n_in,
                              void* d_out, int out_size, void* d_ws,
                              size_t ws_size, hipStream_t stream) {
  const float* x0 = (const float*)d_in[0];  // [4096,32,32]
  const float* w0 = (const float*)d_in[1];  // [1,1024,128]
  const float* w1 = (const float*)d_in[2];  // [1,4096,128]
  float* out = (float*)d_out;               // [4096,256]
  char* ws = (char*)d_ws;

  half_t* Wp0 = (half_t*)(ws);                  // 64*2048 f16 = 256 KB
  half_t* Wp1 = (half_t*)(ws + 64 * 2048 * 2);  // 256*2048 f16 = 1 MB

  hipLaunchKernelGGL(prep_w_kernel, dim3(320), dim3(256), 0, stream, w0, w1,
                     Wp0, Wp1);
  hipLaunchKernelGGL(cin_fused_kernel, dim3(1024), dim3(256), 0, stream, x0,
                     Wp0, Wp1, out);
}

// Round 5
// 211.278 us; speedup vs baseline: 1.0331x; 1.0331x over previous
//
#include <hip/hip_runtime.h>

// CIN (xDeepFM) fully-fused kernel for MI355X.
// B=4096, F=32, D=32; layer1: K1=1024 -> N=128; layer2: K2=4096 -> N=128.
// GEMM rows=(b,d); A generated in registers: A[(b,d)][h*M+m] = x0[b,h,d]*prev[b,m,d].
// mfma_f32_32x32x16_f16: wave = 4 b's (128 rows) x 32 cols.
// R5: ping-pong register pipeline (zero rotation movs). Per gg-step the wave
// issues only: 32 v_pk_mul_f16 + 8 MFMA + 2 global loads + 1 ds_read + ~5 misc.
// Theory: MFMA shares the per-SIMD vector issue path with VALU, so every
// non-MFMA vector instruction is a direct tax on MfmaUtil.

typedef _Float16 half_t;
typedef _Float16 half4v __attribute__((ext_vector_type(4)));
typedef _Float16 half8 __attribute__((ext_vector_type(8)));
typedef float f32x16 __attribute__((ext_vector_type(16)));

// ---- W pack (both filters, one launch): Wp[s][tg][n][8], k=h*M+mc*16+tg*8+j.
__global__ void prep_w_kernel(const float* __restrict__ W0,
                              const float* __restrict__ W1,
                              half_t* __restrict__ Wp0,
                              half_t* __restrict__ Wp1) {
  int gid = blockIdx.x * 256 + threadIdx.x;  // 320*256 threads
  int n = gid & 127;
  int tg = (gid >> 7) & 1;
  int s = gid >> 8;  // 0..319
  const float* W;
  half_t* Wp;
  int M, sl;
  if (s < 64) { W = W0; Wp = Wp0; M = 32; sl = s; }
  else        { W = W1; Wp = Wp1; M = 128; sl = s - 64; }
  int h = sl & 31, mc = sl >> 5;
  int kbase = h * M + mc * 16 + tg * 8;
  half8 v;
#pragma unroll
  for (int j = 0; j < 8; ++j) v[j] = (half_t)W[(size_t)(kbase + j) * 128 + n];
  *(half8*)(Wp + ((size_t)(sl * 2 + tg) * 128 + n) * 8) = v;
}

// swizzled prevT index: logical (row, m) -> halfs offset. 16B-chunk XOR spread.
__device__ __forceinline__ int pswz(int row, int m) {
  return row * 128 + (((m >> 3) ^ (row & 15)) << 3) + (m & 7);
}

__device__ __forceinline__ f32x16 mfma3216(half8 a, half8 b, f32x16 c) {
  return __builtin_amdgcn_mfma_f32_32x32x16_f16(a, b, c, 0, 0, 0);
}

// One CIN layer: MC m-chunks x 32 h. gg unrolled x2 with ping(a)/pong(b)
// register sets -> depth-2 pipeline with zero rotation movs.
// s = 2*g (g = global gg index), x offset repeats every 16 gg.
template <int MC, bool L1>
__device__ __forceinline__ void layer_loop(const half_t* __restrict__ Wp,
                                           const half_t* __restrict__ psrc,
                                           const half_t* __restrict__ xrd,
                                           int woff, int l31, int hi,
                                           f32x16 acc[4]) {
  // preload g=0 (ping) and g=1 (pong):  B: s = {0,1} / {2,3}
  half8 B0a = *(const half8*)(Wp + 0 * 2048 + woff);
  half8 B1a = *(const half8*)(Wp + 1 * 2048 + woff);
  half8 B0b = *(const half8*)(Wp + 2 * 2048 + woff);
  half8 B1b = *(const half8*)(Wp + 3 * 2048 + woff);
  half8 xqa = *(const half8*)(xrd);
  half8 xqb = *(const half8*)(xrd + 256);

  half8 P[4];
#pragma unroll
  for (int rt = 0; rt < 4; ++rt)
    P[rt] = L1 ? *(const half8*)&psrc[(rt * 32 + l31) * 40 + hi * 8]
               : *(const half8*)&psrc[pswz(rt * 32 + l31, hi * 8)];

#pragma unroll 1
  for (int mc = 0; mc < MC; ++mc) {
#pragma unroll 1
    for (int p = 0; p < 8; ++p) {
      const int g0 = mc * 16 + 2 * p;  // even gg (global)
      // ---- even gg: consume ping ----
#pragma unroll
      for (int rt = 0; rt < 4; ++rt)
        acc[rt] = mfma3216(P[rt] * xqa[rt * 2 + 0], B0a, acc[rt]);
#pragma unroll
      for (int rt = 0; rt < 4; ++rt)
        acc[rt] = mfma3216(P[rt] * xqa[rt * 2 + 1], B1a, acc[rt]);
      {  // refill ping for g0+2
        const int sn = (2 * (g0 + 2)) & (MC * 32 - 1);
        B0a = *(const half8*)(Wp + (size_t)sn * 2048 + woff);
        B1a = *(const half8*)(Wp + (size_t)(sn + 1) * 2048 + woff);
        xqa = *(const half8*)(xrd + ((2 * p + 2) & 15) * 256);
      }
      // ---- odd gg: consume pong ----
#pragma unroll
      for (int rt = 0; rt < 4; ++rt)
        acc[rt] = mfma3216(P[rt] * xqb[rt * 2 + 0], B0b, acc[rt]);
#pragma unroll
      for (int rt = 0; rt < 4; ++rt)
        acc[rt] = mfma3216(P[rt] * xqb[rt * 2 + 1], B1b, acc[rt]);
      {  // refill pong for g0+3
        const int sn = (2 * (g0 + 3)) & (MC * 32 - 1);
        B0b = *(const half8*)(Wp + (size_t)sn * 2048 + woff);
        B1b = *(const half8*)(Wp + (size_t)(sn + 1) * 2048 + woff);
        xqb = *(const half8*)(xrd + ((2 * p + 3) & 15) * 256);
      }
    }
    if (mc + 1 < MC) {
      const int mn = (mc + 1) * 16;
#pragma unroll
      for (int rt = 0; rt < 4; ++rt)
        P[rt] = L1 ? *(const half8*)&psrc[(rt * 32 + l31) * 40 + mn + hi * 8]
                   : *(const half8*)&psrc[pswz(rt * 32 + l31, mn + hi * 8)];
    }
  }
}

__global__ __launch_bounds__(256, 4) void cin_fused_kernel(
    const float* __restrict__ x0,    // [4096][32][32] fp32
    const half_t* __restrict__ Wp0,  // 64*2048 halfs
    const half_t* __restrict__ Wp1,  // 256*2048 halfs
    float* __restrict__ out) {       // [4096][256]
  __shared__ half_t xsf3[16 * 256];       // [h>>1][d][bi][h&1] f16 (8 KB)
  __shared__ half_t prevT[4 * 32 * 128];  // swizzled [bi][d][m] (32 KB); alias xT
  half_t* xT = prevT;                     // [bi*32+d][h], stride 40 halfs

  const int tid = threadIdx.x;
  const int b0 = blockIdx.x * 4;

  // ---- stage x0 -> xsf3 and xT ----
  const float4* x4 = (const float4*)(x0 + (size_t)b0 * 1024);
#pragma unroll
  for (int r = 0; r < 4; ++r) {
    int q = r * 256 + tid;
    float4 v = x4[q];
    int e = q * 4;
    int bi = e >> 10, h = (e >> 5) & 31, d0 = e & 31;
    half4v hv = {(half_t)v.x, (half_t)v.y, (half_t)v.z, (half_t)v.w};
#pragma unroll
    for (int j = 0; j < 4; ++j) {
      xsf3[(h >> 1) * 256 + (d0 + j) * 8 + bi * 2 + (h & 1)] = hv[j];
      xT[(bi * 32 + d0 + j) * 40 + h] = hv[j];
    }
  }
  __syncthreads();

  const int lane = tid & 63;
  const int l31 = lane & 31;
  const int hi = lane >> 5;
  const int wave = tid >> 6;
  const int n0 = wave * 32;

  const int woff = hi * 1024 + (n0 + l31) * 8;  // per-lane B offset (halfs)
  const half_t* xrd = &xsf3[l31 * 8];           // + gg*256 halfs

  f32x16 acc[4];
#pragma unroll
  for (int rt = 0; rt < 4; ++rt)
#pragma unroll
    for (int r = 0; r < 16; ++r) acc[rt][r] = 0.f;

  // ================= layer 1 =================
  layer_loop<2, true>(Wp0, xT, xrd, woff, l31, hi, acc);

  __syncthreads();  // all waves done reading xT before prevT overwrite

  // ---- epilogue 1: relu, cur1 -> prevT (swizzled), d-sum -> out[:, 0:128] ----
#pragma unroll
  for (int rt = 0; rt < 4; ++rt) {
    float s = 0.f;
#pragma unroll
    for (int r = 0; r < 16; ++r) {
      float v = acc[rt][r];
      v = v > 0.f ? v : 0.f;
      s += v;
      int d = (r & 3) + ((r >> 2) << 3) + hi * 4;  // C/D row map (32x32)
      prevT[pswz(rt * 32 + d, n0 + l31)] = (half_t)v;
      acc[rt][r] = 0.f;
    }
    s += __shfl_down(s, 32);
    if (lane < 32) out[(size_t)(b0 + rt) * 256 + n0 + lane] = s;
  }
  __syncthreads();

  // ================= layer 2 =================
  layer_loop<8, false>(Wp1, prevT, xrd, woff, l31, hi, acc);

  // ---- epilogue 2: relu, d-sum -> out[:, 128:256] ----
#pragma unroll
  for (int rt = 0; rt < 4; ++rt) {
    float s = 0.f;
#pragma unroll
    for (int r = 0; r < 16; ++r) {
      float v = acc[rt][r];
      s += v > 0.f ? v : 0.f;
    }
    s += __shfl_down(s, 32);
    if (lane < 32) out[(size_t)(b0 + rt) * 256 + 128 + n0 + lane] = s;
  }
}

extern "C" void kernel_launch(void* const* d_in, const int* in_sizes, int n_in,
                              void* d_out, int out_size, void* d_ws,
                              size_t ws_size, hipStream_t stream) {
  const float* x0 = (const float*)d_in[0];  // [4096,32,32]
  const float* w0 = (const float*)d_in[1];  // [1,1024,128]
  const float* w1 = (const float*)d_in[2];  // [1,4096,128]
  float* out = (float*)d_out;               // [4096,256]
  char* ws = (char*)d_ws;

  half_t* Wp0 = (half_t*)(ws);                  // 64*2048 f16 = 256 KB
  half_t* Wp1 = (half_t*)(ws + 64 * 2048 * 2);  // 256*2048 f16 = 1 MB

  hipLaunchKernelGGL(prep_w_kernel, dim3(320), dim3(256), 0, stream, w0, w1,
                     Wp0, Wp1);
  hipLaunchKernelGGL(cin_fused_kernel, dim3(1024), dim3(256), 0, stream, x0,
                     Wp0, Wp1, out);
}